// Round 4
// baseline (142.426 us; speedup 1.0000x reference)
//
#include <hip/hip_runtime.h>
#include <math.h>

// SpectralAngleLoss: B=8192 rows, N=256 peaks, 2000 bins.
//
// Identity: with p[b] the final histogram, dot = sum_i pin_i*q[pbin_i],
// p2 = sum_i pin_i*p[pbin_i], t2 = sum_j tin_j*q[tbin_j] -> 3 scalar LDS
// reads per peak after the scatter; scatter-undo instead of re-zeroing.
//
// Single fused kernel: grid 2048 x 256thr, 16 KB LDS (8 blocks/CU).
// 4 rows sequentially per block; block angle-sum is atomically added to a
// global accumulator (d_ws[0]); a fence+counter (d_ws[1]) lets the last
// block write the mean to d_out. An 8-byte hipMemsetAsync zero-inits both.

#define SAL_NUM_BINS 2000
#define SAL_B 8192
#define SAL_N 256
#define SAL_RPB 4                      // rows per block (sequential)
#define SAL_BLOCKS (SAL_B / SAL_RPB)   // 2048

__global__ __launch_bounds__(256) void sal_fused_kernel(
    const float* __restrict__ pred_mz,
    const float* __restrict__ pred_int,
    const float* __restrict__ targ_mz,
    const float* __restrict__ targ_int,
    const float* __restrict__ targ_mask,
    float* __restrict__ accum,          // d_ws[0], zeroed by memset
    unsigned int* __restrict__ counter, // d_ws[1], zeroed by memset
    float* __restrict__ out)
{
    __shared__ __align__(16) float hist[2][SAL_NUM_BINS];  // [pred/targ][bin]
    __shared__ float rbuf[2][4][3];  // [row parity][wave][dot,p2,t2]
    const int t = threadIdx.x;

    // one-time zero: 4000 floats = 1000 float4 over 256 threads
    {
        float4* h4 = (float4*)&hist[0][0];
        const float4 z = make_float4(0.f, 0.f, 0.f, 0.f);
        #pragma unroll
        for (int i = 0; i < 4; ++i) {
            int idx = t + i * 256;
            if (idx < (2 * SAL_NUM_BINS) / 4) h4[idx] = z;
        }
    }

    // prefetch all rows' peaks (20 coalesced dword loads in flight)
    float pmz[SAL_RPB], pin[SAL_RPB], tmz[SAL_RPB], tin[SAL_RPB];
    #pragma unroll
    for (int r = 0; r < SAL_RPB; ++r) {
        const int base = (blockIdx.x * SAL_RPB + r) * SAL_N + t;
        pmz[r] = pred_mz[base];
        pin[r] = pred_int[base];
        tmz[r] = targ_mz[base];
        tin[r] = targ_int[base] * targ_mask[base];
    }
    __syncthreads();  // zeros visible before first scatter

    float block_sum = 0.0f;  // meaningful on thread 0 only
    const int wave = t >> 6;

    #pragma unroll
    for (int r = 0; r < SAL_RPB; ++r) {
        const int pb = min(max((int)(pmz[r] * 2000.0f), 0), SAL_NUM_BINS - 1);
        const int tb = min(max((int)(tmz[r] * 2000.0f), 0), SAL_NUM_BINS - 1);

        atomicAdd(&hist[0][pb], pin[r]);      // ds_add_f32, ~random bins
        atomicAdd(&hist[1][tb], tin[r]);
        __syncthreads();                      // scatter complete

        const float pv = hist[0][pb];         // p[pbin]
        const float qv = hist[1][pb];         // q[pbin]
        const float tv = hist[1][tb];         // q[tbin]
        float dot = pin[r] * qv;
        float p2  = pin[r] * pv;
        float t2  = tin[r] * tv;
        __syncthreads();                      // reads complete before undo

        hist[0][pb] = 0.0f;                   // scatter-undo (idempotent)
        hist[1][tb] = 0.0f;

        #pragma unroll
        for (int off = 32; off > 0; off >>= 1) {
            dot += __shfl_down(dot, off, 64);
            p2  += __shfl_down(p2,  off, 64);
            t2  += __shfl_down(t2,  off, 64);
        }
        if ((t & 63) == 0) {
            rbuf[r & 1][wave][0] = dot;
            rbuf[r & 1][wave][1] = p2;
            rbuf[r & 1][wave][2] = t2;
        }
        __syncthreads();                      // undo + rbuf visible

        if (t == 0) {
            float d = (rbuf[r & 1][0][0] + rbuf[r & 1][1][0]) +
                      (rbuf[r & 1][2][0] + rbuf[r & 1][3][0]);
            float a = (rbuf[r & 1][0][1] + rbuf[r & 1][1][1]) +
                      (rbuf[r & 1][2][1] + rbuf[r & 1][3][1]);
            float c = (rbuf[r & 1][0][2] + rbuf[r & 1][1][2]) +
                      (rbuf[r & 1][2][2] + rbuf[r & 1][3][2]);
            float pn = fmaxf(sqrtf(a), 1e-8f);
            float tn = fmaxf(sqrtf(c), 1e-8f);
            float cs = d / (pn * tn);
            cs = fminf(fmaxf(cs, -1.0f), 1.0f);
            block_sum += acosf(cs) * (float)(1.0 / M_PI);
        }
    }

    // cross-block accumulation + last-block finalize (threadFence pattern)
    if (t == 0) {
        atomicAdd(accum, block_sum);          // device-scope global atomic
        __threadfence();                      // accum add ordered before count
        unsigned int old = atomicAdd(counter, 1u);
        if (old == SAL_BLOCKS - 1) {
            float total = atomicAdd(accum, 0.0f);  // coherent read of final sum
            out[0] = total * (float)(1.0 / SAL_B);
        }
    }
}

extern "C" void kernel_launch(void* const* d_in, const int* in_sizes, int n_in,
                              void* d_out, int out_size, void* d_ws, size_t ws_size,
                              hipStream_t stream) {
    const float* pred_mz   = (const float*)d_in[0];
    const float* pred_int  = (const float*)d_in[1];
    const float* targ_mz   = (const float*)d_in[2];
    const float* targ_int  = (const float*)d_in[3];
    const float* targ_mask = (const float*)d_in[4];
    float* accum = (float*)d_ws;
    unsigned int* counter = (unsigned int*)d_ws + 1;
    float* out = (float*)d_out;

    hipMemsetAsync(d_ws, 0, 8, stream);   // zero accum + counter (graph-capturable)
    sal_fused_kernel<<<SAL_BLOCKS, 256, 0, stream>>>(pred_mz, pred_int, targ_mz,
                                                     targ_int, targ_mask,
                                                     accum, counter, out);
}

// Round 5
// 108.352 us; speedup vs baseline: 1.3145x; 1.3145x over previous
//
#include <hip/hip_runtime.h>
#include <math.h>

// SpectralAngleLoss: B=8192 rows, N=256 peaks, 2000 bins.
//
// Identity: with p[b] the final histogram, dot = sum_i pin_i*q[pbin_i],
// p2 = sum_i pin_i*p[pbin_i], t2 = sum_j tin_j*q[tbin_j] -> 3 scalar LDS
// reads per peak after the scatter; no 2000-bin scan.
//
// BARRIER-FREE wave-per-row: each of the 4 waves in a block owns a private
// [2][2000] LDS histogram (64 KB/block -> 2 blocks/CU, 8 waves/CU). One row
// per wave, 4 peaks per lane via float4 loads. All ordering is in-wave
// (lockstep + compiler lgkmcnt) -> zero __syncthreads in the kernel.
// Deterministic: per-row angle written to ws, kernel 2 tree-reduces.

#define SAL_NUM_BINS 2000
#define SAL_B 8192
#define SAL_N 256

__global__ __launch_bounds__(256) void sal_row_kernel(
    const float* __restrict__ pred_mz,
    const float* __restrict__ pred_int,
    const float* __restrict__ targ_mz,
    const float* __restrict__ targ_int,
    const float* __restrict__ targ_mask,
    float* __restrict__ row_angle)
{
    __shared__ __align__(16) float hist[4][2][SAL_NUM_BINS];  // 64000 B
    const int t = threadIdx.x;
    const int w = t >> 6;                 // wave in block -> row
    const int l = t & 63;                 // lane
    const int row = blockIdx.x * 4 + w;
    const int base = row * SAL_N;

    // issue all global loads first (16 B/lane, coalesced), zero LDS under them
    const float4 pmz = ((const float4*)(pred_mz   + base))[l];
    const float4 pin = ((const float4*)(pred_int  + base))[l];
    const float4 tmz = ((const float4*)(targ_mz   + base))[l];
    const float4 ti4 = ((const float4*)(targ_int  + base))[l];
    const float4 tm4 = ((const float4*)(targ_mask + base))[l];

    // zero this wave's private 16 KB: 1000 float4 over 64 lanes
    {
        float4* h4 = (float4*)&hist[w][0][0];
        const float4 z = make_float4(0.f, 0.f, 0.f, 0.f);
        #pragma unroll
        for (int i = 0; i < 16; ++i) {
            int idx = l + i * 64;
            if (idx < (2 * SAL_NUM_BINS) / 4) h4[idx] = z;
        }
    }
    // no barrier: region is wave-private; DS ops from this wave are ordered
    // by lgkmcnt before the dependent atomics/reads below.

    const float tinx = ti4.x * tm4.x, tiny_ = ti4.y * tm4.y;
    const float tinz = ti4.z * tm4.z, tinw = ti4.w * tm4.w;

    const int pb0 = min(max((int)(pmz.x * 2000.0f), 0), SAL_NUM_BINS - 1);
    const int pb1 = min(max((int)(pmz.y * 2000.0f), 0), SAL_NUM_BINS - 1);
    const int pb2 = min(max((int)(pmz.z * 2000.0f), 0), SAL_NUM_BINS - 1);
    const int pb3 = min(max((int)(pmz.w * 2000.0f), 0), SAL_NUM_BINS - 1);
    const int tb0 = min(max((int)(tmz.x * 2000.0f), 0), SAL_NUM_BINS - 1);
    const int tb1 = min(max((int)(tmz.y * 2000.0f), 0), SAL_NUM_BINS - 1);
    const int tb2 = min(max((int)(tmz.z * 2000.0f), 0), SAL_NUM_BINS - 1);
    const int tb3 = min(max((int)(tmz.w * 2000.0f), 0), SAL_NUM_BINS - 1);

    atomicAdd(&hist[w][0][pb0], pin.x);   // ds_add_f32, wave-private hist
    atomicAdd(&hist[w][0][pb1], pin.y);
    atomicAdd(&hist[w][0][pb2], pin.z);
    atomicAdd(&hist[w][0][pb3], pin.w);
    atomicAdd(&hist[w][1][tb0], tinx);
    atomicAdd(&hist[w][1][tb1], tiny_);
    atomicAdd(&hist[w][1][tb2], tinz);
    atomicAdd(&hist[w][1][tb3], tinw);
    // compiler inserts lgkmcnt(0) before the dependent reads below

    float dot = 0.f, p2 = 0.f, t2 = 0.f;
    dot = fmaf(pin.x, hist[w][1][pb0], dot);  p2 = fmaf(pin.x, hist[w][0][pb0], p2);
    dot = fmaf(pin.y, hist[w][1][pb1], dot);  p2 = fmaf(pin.y, hist[w][0][pb1], p2);
    dot = fmaf(pin.z, hist[w][1][pb2], dot);  p2 = fmaf(pin.z, hist[w][0][pb2], p2);
    dot = fmaf(pin.w, hist[w][1][pb3], dot);  p2 = fmaf(pin.w, hist[w][0][pb3], p2);
    t2  = fmaf(tinx, hist[w][1][tb0], t2);
    t2  = fmaf(tiny_, hist[w][1][tb1], t2);
    t2  = fmaf(tinz, hist[w][1][tb2], t2);
    t2  = fmaf(tinw, hist[w][1][tb3], t2);

    // wave64 shuffle reduction (no LDS, no barrier)
    #pragma unroll
    for (int off = 32; off > 0; off >>= 1) {
        dot += __shfl_down(dot, off, 64);
        p2  += __shfl_down(p2,  off, 64);
        t2  += __shfl_down(t2,  off, 64);
    }
    if (l == 0) {
        float pn = fmaxf(sqrtf(p2), 1e-8f);
        float tn = fmaxf(sqrtf(t2), 1e-8f);
        float cs = dot / (pn * tn);
        cs = fminf(fmaxf(cs, -1.0f), 1.0f);
        row_angle[row] = acosf(cs) * (float)(1.0 / M_PI);
    }
}

__global__ __launch_bounds__(256) void sal_reduce_kernel(
    const float* __restrict__ row_angle, float* __restrict__ out)
{
    const int t = threadIdx.x;
    const float4* ra4 = (const float4*)row_angle;
    float s = 0.0f;
    #pragma unroll
    for (int i = 0; i < SAL_B / 4 / 256; ++i) {   // 2048 float4
        float4 v = ra4[t + i * 256];
        s += (v.x + v.y) + (v.z + v.w);
    }
    #pragma unroll
    for (int off = 32; off > 0; off >>= 1) s += __shfl_down(s, off, 64);
    __shared__ float rbuf[4];
    if ((t & 63) == 0) rbuf[t >> 6] = s;
    __syncthreads();
    if (t == 0) out[0] = ((rbuf[0] + rbuf[1]) + (rbuf[2] + rbuf[3])) * (float)(1.0 / SAL_B);
}

extern "C" void kernel_launch(void* const* d_in, const int* in_sizes, int n_in,
                              void* d_out, int out_size, void* d_ws, size_t ws_size,
                              hipStream_t stream) {
    const float* pred_mz   = (const float*)d_in[0];
    const float* pred_int  = (const float*)d_in[1];
    const float* targ_mz   = (const float*)d_in[2];
    const float* targ_int  = (const float*)d_in[3];
    const float* targ_mask = (const float*)d_in[4];
    float* row_angle = (float*)d_ws;   // 8192 floats, fully overwritten
    float* out = (float*)d_out;

    sal_row_kernel<<<SAL_B / 4, 256, 0, stream>>>(pred_mz, pred_int, targ_mz,
                                                  targ_int, targ_mask, row_angle);
    sal_reduce_kernel<<<1, 256, 0, stream>>>(row_angle, out);
}

// Round 6
// 105.253 us; speedup vs baseline: 1.3532x; 1.0294x over previous
//
#include <hip/hip_runtime.h>
#include <math.h>

// SpectralAngleLoss: B=8192 rows, N=256 peaks, 2000 bins.
//
// Identity: with p[b] the final histogram, dot = sum_i pin_i*q[pbin_i],
// p2 = sum_i pin_i*p[pbin_i], t2 = sum_j tin_j*q[tbin_j] -> 3 scalar LDS
// reads per peak after the scatter; no 2000-bin scan.
//
// BARRIER-FREE wave-private histograms: each of the 4 waves in a block owns
// a [2][2000] LDS region (64 KB/block -> 2 blocks/CU, 8 waves/CU) and
// processes 2 rows sequentially: zero once, scatter/gather row A, scatter-
// undo (write 0 back to touched bins), then row B. All DS ops are wave-
// ordered (lockstep + lgkmcnt) -> zero __syncthreads. Wave writes the sum
// of its 2 angles; kernel 2 tree-reduces 4096 partials. Fully deterministic.

#define SAL_NUM_BINS 2000
#define SAL_B 8192
#define SAL_N 256

__device__ __forceinline__ float sal_row_angle(
    float* __restrict__ hp, float* __restrict__ hq,   // wave-private hists
    const float4& pmz, const float4& pin,
    const float4& tmz, const float4& tin,
    bool undo)
{
    const int pb0 = min(max((int)(pmz.x * 2000.0f), 0), SAL_NUM_BINS - 1);
    const int pb1 = min(max((int)(pmz.y * 2000.0f), 0), SAL_NUM_BINS - 1);
    const int pb2 = min(max((int)(pmz.z * 2000.0f), 0), SAL_NUM_BINS - 1);
    const int pb3 = min(max((int)(pmz.w * 2000.0f), 0), SAL_NUM_BINS - 1);
    const int tb0 = min(max((int)(tmz.x * 2000.0f), 0), SAL_NUM_BINS - 1);
    const int tb1 = min(max((int)(tmz.y * 2000.0f), 0), SAL_NUM_BINS - 1);
    const int tb2 = min(max((int)(tmz.z * 2000.0f), 0), SAL_NUM_BINS - 1);
    const int tb3 = min(max((int)(tmz.w * 2000.0f), 0), SAL_NUM_BINS - 1);

    atomicAdd(&hp[pb0], pin.x);   // ds_add_f32, wave-private region
    atomicAdd(&hp[pb1], pin.y);
    atomicAdd(&hp[pb2], pin.z);
    atomicAdd(&hp[pb3], pin.w);
    atomicAdd(&hq[tb0], tin.x);
    atomicAdd(&hq[tb1], tin.y);
    atomicAdd(&hq[tb2], tin.z);
    atomicAdd(&hq[tb3], tin.w);
    // compiler orders dependent ds_reads after the atomics via lgkmcnt

    float dot = 0.f, p2 = 0.f, t2 = 0.f;
    dot = fmaf(pin.x, hq[pb0], dot);  p2 = fmaf(pin.x, hp[pb0], p2);
    dot = fmaf(pin.y, hq[pb1], dot);  p2 = fmaf(pin.y, hp[pb1], p2);
    dot = fmaf(pin.z, hq[pb2], dot);  p2 = fmaf(pin.z, hp[pb2], p2);
    dot = fmaf(pin.w, hq[pb3], dot);  p2 = fmaf(pin.w, hp[pb3], p2);
    t2  = fmaf(tin.x, hq[tb0], t2);
    t2  = fmaf(tin.y, hq[tb1], t2);
    t2  = fmaf(tin.z, hq[tb2], t2);
    t2  = fmaf(tin.w, hq[tb3], t2);

    if (undo) {                       // in-order DS: reads above complete first
        hp[pb0] = 0.0f; hp[pb1] = 0.0f; hp[pb2] = 0.0f; hp[pb3] = 0.0f;
        hq[tb0] = 0.0f; hq[tb1] = 0.0f; hq[tb2] = 0.0f; hq[tb3] = 0.0f;
    }

    #pragma unroll
    for (int off = 32; off > 0; off >>= 1) {
        dot += __shfl_down(dot, off, 64);
        p2  += __shfl_down(p2,  off, 64);
        t2  += __shfl_down(t2,  off, 64);
    }
    float pn = fmaxf(sqrtf(p2), 1e-8f);
    float tn = fmaxf(sqrtf(t2), 1e-8f);
    float cs = dot / (pn * tn);
    cs = fminf(fmaxf(cs, -1.0f), 1.0f);
    return acosf(cs) * (float)(1.0 / M_PI);   // valid on lane 0
}

__global__ __launch_bounds__(256) void sal_row_kernel(
    const float* __restrict__ pred_mz,
    const float* __restrict__ pred_int,
    const float* __restrict__ targ_mz,
    const float* __restrict__ targ_int,
    const float* __restrict__ targ_mask,
    float* __restrict__ wave_partial)     // 4096 entries: sum of 2 angles
{
    __shared__ __align__(16) float hist[4][2][SAL_NUM_BINS];  // 64000 B
    const int t = threadIdx.x;
    const int w = t >> 6;                 // wave in block
    const int l = t & 63;                 // lane
    const int rowA = blockIdx.x * 8 + w * 2;     // two consecutive rows/wave
    const int baseA = rowA * SAL_N;
    const int baseB = baseA + SAL_N;

    // issue both rows' global loads first (10 x 16B/lane, coalesced)
    const float4 pmzA = ((const float4*)(pred_mz   + baseA))[l];
    const float4 pinA = ((const float4*)(pred_int  + baseA))[l];
    const float4 tmzA = ((const float4*)(targ_mz   + baseA))[l];
    const float4 ti4A = ((const float4*)(targ_int  + baseA))[l];
    const float4 tm4A = ((const float4*)(targ_mask + baseA))[l];
    const float4 pmzB = ((const float4*)(pred_mz   + baseB))[l];
    const float4 pinB = ((const float4*)(pred_int  + baseB))[l];
    const float4 tmzB = ((const float4*)(targ_mz   + baseB))[l];
    const float4 ti4B = ((const float4*)(targ_int  + baseB))[l];
    const float4 tm4B = ((const float4*)(targ_mask + baseB))[l];

    // zero this wave's private 16 KB under the loads: 1000 float4 / 64 lanes
    {
        float4* h4 = (float4*)&hist[w][0][0];
        const float4 z = make_float4(0.f, 0.f, 0.f, 0.f);
        #pragma unroll
        for (int i = 0; i < 16; ++i) {
            int idx = l + i * 64;
            if (idx < (2 * SAL_NUM_BINS) / 4) h4[idx] = z;
        }
    }

    float* hp = &hist[w][0][0];
    float* hq = &hist[w][1][0];

    const float4 tinA = make_float4(ti4A.x * tm4A.x, ti4A.y * tm4A.y,
                                    ti4A.z * tm4A.z, ti4A.w * tm4A.w);
    const float4 tinB = make_float4(ti4B.x * tm4B.x, ti4B.y * tm4B.y,
                                    ti4B.z * tm4B.z, ti4B.w * tm4B.w);

    const float angA = sal_row_angle(hp, hq, pmzA, pinA, tmzA, tinA, true);
    const float angB = sal_row_angle(hp, hq, pmzB, pinB, tmzB, tinB, false);

    if (l == 0) wave_partial[blockIdx.x * 4 + w] = angA + angB;
}

__global__ __launch_bounds__(256) void sal_reduce_kernel(
    const float* __restrict__ wave_partial, float* __restrict__ out)
{
    const int t = threadIdx.x;
    const float4* wp4 = (const float4*)wave_partial;
    float s = 0.0f;
    #pragma unroll
    for (int i = 0; i < 4096 / 4 / 256; ++i) {   // 1024 float4
        float4 v = wp4[t + i * 256];
        s += (v.x + v.y) + (v.z + v.w);
    }
    #pragma unroll
    for (int off = 32; off > 0; off >>= 1) s += __shfl_down(s, off, 64);
    __shared__ float rbuf[4];
    if ((t & 63) == 0) rbuf[t >> 6] = s;
    __syncthreads();
    if (t == 0) out[0] = ((rbuf[0] + rbuf[1]) + (rbuf[2] + rbuf[3])) * (float)(1.0 / SAL_B);
}

extern "C" void kernel_launch(void* const* d_in, const int* in_sizes, int n_in,
                              void* d_out, int out_size, void* d_ws, size_t ws_size,
                              hipStream_t stream) {
    const float* pred_mz   = (const float*)d_in[0];
    const float* pred_int  = (const float*)d_in[1];
    const float* targ_mz   = (const float*)d_in[2];
    const float* targ_int  = (const float*)d_in[3];
    const float* targ_mask = (const float*)d_in[4];
    float* wave_partial = (float*)d_ws;   // 4096 floats, fully overwritten
    float* out = (float*)d_out;

    sal_row_kernel<<<SAL_B / 8, 256, 0, stream>>>(pred_mz, pred_int, targ_mz,
                                                  targ_int, targ_mask, wave_partial);
    sal_reduce_kernel<<<1, 256, 0, stream>>>(wave_partial, out);
}